// Round 5
// baseline (148.642 us; speedup 1.0000x reference)
//
#include <hip/hip_runtime.h>

#define T_TOKENS 16384
#define DIM 2048
#define NE 8
#define QOUT 2048
#define LSCALE 2.0f

typedef __attribute__((ext_vector_type(4))) float f32x4;
typedef __attribute__((ext_vector_type(8))) short s16x8;
typedef __attribute__((ext_vector_type(4))) short s16x4;

__device__ __forceinline__ short f2bf(float f) {
  unsigned u = __builtin_bit_cast(unsigned, f);
  u += 0x7fffu + ((u >> 16) & 1u);   // round-to-nearest-even
  return (short)(u >> 16);
}

// LDS-only barrier: drains lgkm (ds_write visibility) but leaves global
// prefetch loads (vmcnt) in flight across the barrier.
__device__ __forceinline__ void barrier_lds() {
  asm volatile("s_waitcnt lgkmcnt(0)" ::: "memory");
  __builtin_amdgcn_s_barrier();
}

// ---------------------------------------------------------------------------
// Pack LoRA weights (f32) into bf16 MFMA-fragment layout.
// lora_a [E][D][R]  -> P1[d8][col=e*16+r][j]  (d = d8*8+j), col in [0,128)
// lora_b [E][R][QO] -> P2[k8][c][j]           (k = k8*8+j = e*16+r)
// ---------------------------------------------------------------------------
__global__ __launch_bounds__(256) void k_pack(
    const float* __restrict__ qa, const float* __restrict__ qb,
    const float* __restrict__ va, const float* __restrict__ vb,
    short* __restrict__ Bq1, short* __restrict__ Bv1,
    short* __restrict__ Bq2, short* __restrict__ Bv2) {
  int tid = blockIdx.x * 256 + threadIdx.x;  // 131072 threads
  if (tid < 65536) {
    int mat = tid >> 15;
    int idx = tid & 32767;          // d8*128 + col
    int d8 = idx >> 7, c = idx & 127;
    int e = c >> 4, r = c & 15;
    const float* src = mat ? va : qa;
    short* dst = mat ? Bv1 : Bq1;
    s16x8 v;
#pragma unroll
    for (int j = 0; j < 8; ++j)
      v[j] = f2bf(src[((size_t)e * DIM + d8 * 8 + j) * 16 + r]);
    *(s16x8*)(dst + (size_t)idx * 8) = v;
  } else {
    int t2 = tid - 65536;
    int mat = t2 >> 15;
    int idx = t2 & 32767;           // k8*2048 + c
    int k8 = idx >> 11, c = idx & 2047;
    const float* src = mat ? vb : qb;
    short* dst = mat ? Bv2 : Bq2;
    s16x8 v;
#pragma unroll
    for (int j = 0; j < 8; ++j)
      v[j] = f2bf(src[(size_t)(k8 * 8 + j) * QOUT + c]);
    *(s16x8*)(dst + (size_t)idx * 8) = v;
  }
}

// ---------------------------------------------------------------------------
// Fused stage 1: routing (f32-exact) + low = (h @ Acat) * w.
// Block = 64 tokens x 256 cols, 8 waves.  Depth-2 pipeline on the h load
// (3 live float4) so the HBM load issues ~2 K-steps before its ds_write;
// B-frags depth-1 (L2-resident).  LDS-only barrier keeps vmcnt in flight.
// ---------------------------------------------------------------------------
__global__ __launch_bounds__(512, 4) void k_s1(
    const float* __restrict__ h, const float* __restrict__ rw,
    const short* __restrict__ Bq1, const short* __restrict__ Bv1,
    short* __restrict__ lowq, short* __restrict__ lowv) {
  __shared__ float rwl[NE * DIM];       // 64 KB
  __shared__ short At[2][64][40];       // 10 KB, padded rows (80 B)
  __shared__ float wl[64][NE];          // 2 KB

  const int tid = threadIdx.x;
  const int lane = tid & 63, wv = tid >> 6;
  const int lrow = lane & 15, lk = lane >> 4;
  const int row0 = blockIdx.x * 64;
  const int rh = wv >> 2;               // token half
  const int c0 = (wv & 3) * 64;         // col group
  const int r = tid >> 3;               // 0..63
  const int kq = (tid & 7) * 4;

  {  // stage router weights (16384 f32) into LDS
    const float4* src = (const float4*)rw;
    float4* dst = (float4*)rwl;
#pragma unroll
    for (int i = 0; i < 8; ++i) dst[tid + i * 512] = src[tid + i * 512];
  }
  __syncthreads();

  const float* hrow = h + (size_t)(row0 + r) * DIM;
  const short* bp[4]; int cc4[4];
#pragma unroll
  for (int ct = 0; ct < 4; ++ct) {
    int c = c0 + ct * 16 + lrow;
    bp[ct] = (c < 128) ? Bq1 : Bv1;
    cc4[ct] = c & 127;
  }

  // prologue: hv for kb=0 and kb=32 in flight; B for kb=0
  float4 hv_c = *(const float4*)(hrow + kq);
  float4 hv_n = *(const float4*)(hrow + 32 + kq);
  s16x8 b[4];
#pragma unroll
  for (int ct = 0; ct < 4; ++ct)
    b[ct] = *(const s16x8*)(bp[ct] + ((size_t)lk * 128 + cc4[ct]) * 8);

  float lg[NE] = {0.f, 0.f, 0.f, 0.f, 0.f, 0.f, 0.f, 0.f};
  f32x4 acc[2][4] = {};
  int cur = 0;

  for (int kb = 0; kb < DIM; kb += 32) {
    const int kn1 = (kb + 32) & (DIM - 1);   // wraps (dead) on tail iters
    const int kn2 = (kb + 64) & (DIM - 1);
    float4 hv_n2 = *(const float4*)(hrow + kn2 + kq);
    s16x8 bn[4];
#pragma unroll
    for (int ct = 0; ct < 4; ++ct)
      bn[ct] = *(const s16x8*)(bp[ct] + ((size_t)((kn1 >> 3) + lk) * 128 + cc4[ct]) * 8);
    // routing partials (wave-broadcast LDS reads, f32 VALU)
#pragma unroll
    for (int e = 0; e < NE; ++e) {
      float4 rv = *(const float4*)&rwl[e * DIM + kb + kq];
      lg[e] += hv_c.x * rv.x + hv_c.y * rv.y + hv_c.z * rv.z + hv_c.w * rv.w;
    }
    // convert + stage A tile
    s16x4 hb4;
    hb4[0] = f2bf(hv_c.x); hb4[1] = f2bf(hv_c.y);
    hb4[2] = f2bf(hv_c.z); hb4[3] = f2bf(hv_c.w);
    *(s16x4*)&At[cur][r][kq] = hb4;
    barrier_lds();                          // lgkm drain only; vmcnt stays
    s16x8 a[2];
#pragma unroll
    for (int rt = 0; rt < 2; ++rt)
      a[rt] = *(const s16x8*)&At[cur][rh * 32 + rt * 16 + lrow][lk * 8];
#pragma unroll
    for (int rt = 0; rt < 2; ++rt)
#pragma unroll
      for (int ct = 0; ct < 4; ++ct)
        acc[rt][ct] = __builtin_amdgcn_mfma_f32_16x16x32_bf16(b[ct], a[rt], acc[rt][ct], 0, 0, 0);
    hv_c = hv_n; hv_n = hv_n2;
#pragma unroll
    for (int ct = 0; ct < 4; ++ct) b[ct] = bn[ct];
    cur ^= 1;
  }

  // reduce logits across the 8 k-lanes of each row
#pragma unroll
  for (int e = 0; e < NE; ++e) {
    lg[e] += __shfl_xor(lg[e], 1, 64);
    lg[e] += __shfl_xor(lg[e], 2, 64);
    lg[e] += __shfl_xor(lg[e], 4, 64);
  }
  // softmax + top-2 (redundant across 8 lanes of a row; deterministic)
  float mx = lg[0];
#pragma unroll
  for (int e = 1; e < NE; ++e) mx = fmaxf(mx, lg[e]);
  float p[NE], sum = 0.f;
#pragma unroll
  for (int e = 0; e < NE; ++e) { p[e] = expf(lg[e] - mx); sum += p[e]; }
  int i1 = 0; float v1 = p[0];
#pragma unroll
  for (int e = 1; e < NE; ++e) if (p[e] > v1) { v1 = p[e]; i1 = e; }
  float v2 = -1.f; int i2 = 0;
#pragma unroll
  for (int e = 0; e < NE; ++e) if (e != i1 && p[e] > v2) { v2 = p[e]; i2 = e; }
  float s1 = v1 / sum, s2 = v2 / sum;
  float dn = s1 + s2 + 1e-20f;
  float w1 = s1 / dn * LSCALE, w2 = s2 / dn * LSCALE;
  int el = tid & 7;
  wl[r][el] = (el == i1) ? w1 : ((el == i2) ? w2 : 0.f);
  __syncthreads();

  // scale + store low (operand-swapped layout: token=lane&15, cols=lk*4+j)
#pragma unroll
  for (int rt = 0; rt < 2; ++rt)
#pragma unroll
    for (int ct = 0; ct < 4; ++ct) {
      int rr = rh * 32 + rt * 16 + lrow;
      int t = row0 + rr;
      int col = c0 + ct * 16 + lk * 4;
      int cc = col & 127;
      int e = cc >> 4;
      short* op = (col < 128) ? lowq : lowv;
      float wgt = wl[rr][e];
      s16x4 v;
#pragma unroll
      for (int j = 0; j < 4; ++j) v[j] = f2bf(acc[rt][ct][j] * wgt);
      *(s16x4*)(op + (size_t)t * 128 + cc) = v;
    }
}

// ---------------------------------------------------------------------------
// Stage 2: delta = low[T,128] @ B[128,2048].  Block = 64 tokens x 1024 cols.
// A-frags (K=128) preloaded; flattened (sub,kk) 16-iter pipeline with
// depth-1 B prefetch so L2 latency + store drain hide under MFMA.
// ---------------------------------------------------------------------------
__global__ __launch_bounds__(256, 3) void k_up(
    const short* __restrict__ lowq, const short* __restrict__ lowv,
    const short* __restrict__ Bq2, const short* __restrict__ Bv2,
    float* __restrict__ out) {
  const int lane = threadIdx.x & 63, wv = threadIdx.x >> 6;
  const int lrow = lane & 15, lk = lane >> 4;
  const int row0 = blockIdx.x * 64;
  const int m = blockIdx.y >> 1;
  const int half = blockIdx.y & 1;
  const short* low = m ? lowv : lowq;
  const short* B = m ? Bv2 : Bq2;
  float* op = out + (size_t)m * T_TOKENS * QOUT;

  s16x8 a[4][4];
#pragma unroll
  for (int rt = 0; rt < 4; ++rt)
#pragma unroll
    for (int kk = 0; kk < 4; ++kk)
      a[rt][kk] = *(const s16x8*)(low + (size_t)(row0 + rt * 16 + lrow) * 128 + kk * 32 + lk * 8);

  // prologue B load: (sub=0, kk=0)
  s16x8 bc[4], bn[4];
#pragma unroll
  for (int ct = 0; ct < 4; ++ct) {
    int c = half * 1024 + wv * 64 + ct * 16 + lrow;
    bc[ct] = *(const s16x8*)(B + ((size_t)lk * QOUT + c) * 8);
  }

  f32x4 acc[4][4] = {};
#pragma unroll
  for (int it = 0; it < 16; ++it) {
    const int sub = it >> 2, kk = it & 3;
    const int itn = (it + 1) & 15;           // wraps (dead) on last iter
    const int subn = itn >> 2, kkn = itn & 3;
    // issue next-iteration B loads before compute
#pragma unroll
    for (int ct = 0; ct < 4; ++ct) {
      int c = half * 1024 + subn * 256 + wv * 64 + ct * 16 + lrow;
      bn[ct] = *(const s16x8*)(B + ((size_t)(kkn * 4 + lk) * QOUT + c) * 8);
    }
#pragma unroll
    for (int rt = 0; rt < 4; ++rt)
#pragma unroll
      for (int ct = 0; ct < 4; ++ct)
        acc[rt][ct] = __builtin_amdgcn_mfma_f32_16x16x32_bf16(bc[ct], a[rt][kk], acc[rt][ct], 0, 0, 0);
    if (kk == 3) {
      int cb = half * 1024 + sub * 256 + wv * 64;
#pragma unroll
      for (int rt = 0; rt < 4; ++rt)
#pragma unroll
        for (int ct = 0; ct < 4; ++ct) {
          int t = row0 + rt * 16 + lrow;
          int col = cb + ct * 16 + lk * 4;
          *(f32x4*)(op + (size_t)t * QOUT + col) = acc[rt][ct];
          acc[rt][ct] = (f32x4){0.f, 0.f, 0.f, 0.f};
        }
    }
#pragma unroll
    for (int ct = 0; ct < 4; ++ct) bc[ct] = bn[ct];
  }
}

extern "C" void kernel_launch(void* const* d_in, const int* in_sizes, int n_in,
                              void* d_out, int out_size, void* d_ws, size_t ws_size,
                              hipStream_t stream) {
  const float* h  = (const float*)d_in[0];
  const float* rw = (const float*)d_in[1];
  const float* qa = (const float*)d_in[2];
  const float* qb = (const float*)d_in[3];
  const float* va = (const float*)d_in[4];
  const float* vb = (const float*)d_in[5];
  float* out = (float*)d_out;
  char* ws = (char*)d_ws;

  short* Bq1 = (short*)(ws);                    // 512 KB each
  short* Bv1 = (short*)(ws + (512 << 10));
  short* Bq2 = (short*)(ws + (1024 << 10));
  short* Bv2 = (short*)(ws + (1536 << 10));
  short* lowq = (short*)(ws + (2 << 20));       // 4 MB each
  short* lowv = (short*)(ws + (6 << 20));

  k_pack<<<512, 256, 0, stream>>>(qa, qb, va, vb, Bq1, Bv1, Bq2, Bv2);
  k_s1<<<T_TOKENS / 64, 512, 0, stream>>>(h, rw, Bq1, Bv1, lowq, lowv);
  dim3 g2(T_TOKENS / 64, 4);
  k_up<<<g2, 256, 0, stream>>>(lowq, lowv, Bq2, Bv2, out);
}

// Round 6
// 145.465 us; speedup vs baseline: 1.0218x; 1.0218x over previous
//
#include <hip/hip_runtime.h>

#define T_TOKENS 16384
#define DIM 2048
#define NE 8
#define QOUT 2048
#define LSCALE 2.0f

typedef __attribute__((ext_vector_type(4))) float f32x4;
typedef __attribute__((ext_vector_type(8))) short s16x8;
typedef __attribute__((ext_vector_type(4))) short s16x4;

__device__ __forceinline__ short f2bf(float f) {
  unsigned u = __builtin_bit_cast(unsigned, f);
  u += 0x7fffu + ((u >> 16) & 1u);   // round-to-nearest-even
  return (short)(u >> 16);
}

// LDS-only barrier: drains lgkm (ds_write visibility) but leaves global
// prefetch loads (vmcnt) in flight across the barrier.
__device__ __forceinline__ void barrier_lds() {
  asm volatile("s_waitcnt lgkmcnt(0)" ::: "memory");
  __builtin_amdgcn_s_barrier();
}

// ---------------------------------------------------------------------------
// Pack LoRA weights (f32) into bf16 MFMA-fragment layout.
// lora_a [E][D][R]  -> P1[d8][col=e*16+r][j]  (d = d8*8+j), col in [0,128)
// lora_b [E][R][QO] -> P2[k8][c][j]           (k = k8*8+j = e*16+r)
// ---------------------------------------------------------------------------
__global__ __launch_bounds__(256) void k_pack(
    const float* __restrict__ qa, const float* __restrict__ qb,
    const float* __restrict__ va, const float* __restrict__ vb,
    short* __restrict__ Bq1, short* __restrict__ Bv1,
    short* __restrict__ Bq2, short* __restrict__ Bv2) {
  int tid = blockIdx.x * 256 + threadIdx.x;  // 131072 threads
  if (tid < 65536) {
    int mat = tid >> 15;
    int idx = tid & 32767;          // d8*128 + col
    int d8 = idx >> 7, c = idx & 127;
    int e = c >> 4, r = c & 15;
    const float* src = mat ? va : qa;
    short* dst = mat ? Bv1 : Bq1;
    s16x8 v;
#pragma unroll
    for (int j = 0; j < 8; ++j)
      v[j] = f2bf(src[((size_t)e * DIM + d8 * 8 + j) * 16 + r]);
    *(s16x8*)(dst + (size_t)idx * 8) = v;
  } else {
    int t2 = tid - 65536;
    int mat = t2 >> 15;
    int idx = t2 & 32767;           // k8*2048 + c
    int k8 = idx >> 11, c = idx & 2047;
    const float* src = mat ? vb : qb;
    short* dst = mat ? Bv2 : Bq2;
    s16x8 v;
#pragma unroll
    for (int j = 0; j < 8; ++j)
      v[j] = f2bf(src[(size_t)(k8 * 8 + j) * QOUT + c]);
    *(s16x8*)(dst + (size_t)idx * 8) = v;
  }
}

// ---------------------------------------------------------------------------
// Fused stage 1: routing (f32-exact) + low = (h @ Acat) * w.
// Block = 32 tokens x 256 cols, 4 waves, grid 512 -> 2 blocks/CU (LDS 70KB)
// so independent blocks cover each other's barrier stalls.  K-loop unrolled
// 4x so prefetch regs are renamed (no wait-forcing rotation copies).
// ---------------------------------------------------------------------------
__global__ __launch_bounds__(256) void k_s1(
    const float* __restrict__ h, const float* __restrict__ rw,
    const short* __restrict__ Bq1, const short* __restrict__ Bv1,
    short* __restrict__ lowq, short* __restrict__ lowv) {
  __shared__ float rwl[NE * DIM];       // 64 KB
  __shared__ short At[2][32][40];       // 5 KB, padded rows (80 B)
  __shared__ float wl[32][NE];          // 1 KB

  const int tid = threadIdx.x;
  const int lane = tid & 63, wv = tid >> 6;
  const int lrow = lane & 15, lk = lane >> 4;
  const int row0 = blockIdx.x * 32;
  const int c0 = wv * 64;
  const int r = tid >> 3;               // 0..31
  const int kq = (tid & 7) * 4;

  {  // stage router weights (16384 f32) into LDS
    const float4* src = (const float4*)rw;
    float4* dst = (float4*)rwl;
#pragma unroll
    for (int i = 0; i < 16; ++i) dst[tid + i * 256] = src[tid + i * 256];
  }
  __syncthreads();

  const float* hrow = h + (size_t)(row0 + r) * DIM;
  const short* bp[4]; int cc4[4];
#pragma unroll
  for (int ct = 0; ct < 4; ++ct) {
    int c = c0 + ct * 16 + lrow;
    bp[ct] = (c < 128) ? Bq1 : Bv1;
    cc4[ct] = c & 127;
  }

  // prologue: hv for kb=0 and kb=32 in flight; B for kb=0
  float4 hv_c = *(const float4*)(hrow + kq);
  float4 hv_n = *(const float4*)(hrow + 32 + kq);
  s16x8 b[4];
#pragma unroll
  for (int ct = 0; ct < 4; ++ct)
    b[ct] = *(const s16x8*)(bp[ct] + ((size_t)lk * 128 + cc4[ct]) * 8);

  float lg[NE] = {0.f, 0.f, 0.f, 0.f, 0.f, 0.f, 0.f, 0.f};
  f32x4 acc[2][4] = {};

#pragma unroll 4
  for (int kb = 0; kb < DIM; kb += 32) {
    const int cur = (kb >> 5) & 1;
    const int kn1 = (kb + 32) & (DIM - 1);   // wraps (dead value) on tails
    const int kn2 = (kb + 64) & (DIM - 1);
    float4 hv_n2 = *(const float4*)(hrow + kn2 + kq);
    s16x8 bn[4];
#pragma unroll
    for (int ct = 0; ct < 4; ++ct)
      bn[ct] = *(const s16x8*)(bp[ct] + ((size_t)((kn1 >> 3) + lk) * 128 + cc4[ct]) * 8);
    // routing partials (wave-broadcast LDS reads, f32 VALU)
#pragma unroll
    for (int e = 0; e < NE; ++e) {
      float4 rv = *(const float4*)&rwl[e * DIM + kb + kq];
      lg[e] += hv_c.x * rv.x + hv_c.y * rv.y + hv_c.z * rv.z + hv_c.w * rv.w;
    }
    // convert + stage A tile
    s16x4 hb4;
    hb4[0] = f2bf(hv_c.x); hb4[1] = f2bf(hv_c.y);
    hb4[2] = f2bf(hv_c.z); hb4[3] = f2bf(hv_c.w);
    *(s16x4*)&At[cur][r][kq] = hb4;
    barrier_lds();                          // lgkm drain only; vmcnt stays
    s16x8 a[2];
#pragma unroll
    for (int rt = 0; rt < 2; ++rt)
      a[rt] = *(const s16x8*)&At[cur][rt * 16 + lrow][lk * 8];
#pragma unroll
    for (int rt = 0; rt < 2; ++rt)
#pragma unroll
      for (int ct = 0; ct < 4; ++ct)
        acc[rt][ct] = __builtin_amdgcn_mfma_f32_16x16x32_bf16(b[ct], a[rt], acc[rt][ct], 0, 0, 0);
    hv_c = hv_n; hv_n = hv_n2;
#pragma unroll
    for (int ct = 0; ct < 4; ++ct) b[ct] = bn[ct];
  }

  // reduce logits across the 8 k-lanes of each row
#pragma unroll
  for (int e = 0; e < NE; ++e) {
    lg[e] += __shfl_xor(lg[e], 1, 64);
    lg[e] += __shfl_xor(lg[e], 2, 64);
    lg[e] += __shfl_xor(lg[e], 4, 64);
  }
  // softmax + top-2 (redundant across 8 lanes of a row; deterministic)
  float mx = lg[0];
#pragma unroll
  for (int e = 1; e < NE; ++e) mx = fmaxf(mx, lg[e]);
  float p[NE], sum = 0.f;
#pragma unroll
  for (int e = 0; e < NE; ++e) { p[e] = expf(lg[e] - mx); sum += p[e]; }
  int i1 = 0; float v1 = p[0];
#pragma unroll
  for (int e = 1; e < NE; ++e) if (p[e] > v1) { v1 = p[e]; i1 = e; }
  float v2 = -1.f; int i2 = 0;
#pragma unroll
  for (int e = 0; e < NE; ++e) if (e != i1 && p[e] > v2) { v2 = p[e]; i2 = e; }
  float s1 = v1 / sum, s2 = v2 / sum;
  float dn = s1 + s2 + 1e-20f;
  float w1 = s1 / dn * LSCALE, w2 = s2 / dn * LSCALE;
  int el = tid & 7;
  wl[r][el] = (el == i1) ? w1 : ((el == i2) ? w2 : 0.f);
  __syncthreads();

  // scale + store low (operand-swapped layout: token=lane&15, cols=lk*4+j)
#pragma unroll
  for (int rt = 0; rt < 2; ++rt)
#pragma unroll
    for (int ct = 0; ct < 4; ++ct) {
      int rr = rt * 16 + lrow;
      int t = row0 + rr;
      int col = c0 + ct * 16 + lk * 4;
      int cc = col & 127;
      int e = cc >> 4;
      short* op = (col < 128) ? lowq : lowv;
      float wgt = wl[rr][e];
      s16x4 v;
#pragma unroll
      for (int j = 0; j < 4; ++j) v[j] = f2bf(acc[rt][ct][j] * wgt);
      *(s16x4*)(op + (size_t)t * 128 + cc) = v;
    }
}

// ---------------------------------------------------------------------------
// Stage 2: delta = low[T,128] @ B[128,2048].  Block = 64 tokens x 1024 cols.
// A-frags (K=128) preloaded; flattened (sub,kk) 16-iter pipeline, depth-1 B
// prefetch (fully unrolled -> renamed).  launch_bounds(256,2): no spill.
// Nontemporal f32x4 stores: 256 MB output bypasses L2, keeps B2 hot.
// ---------------------------------------------------------------------------
__global__ __launch_bounds__(256, 2) void k_up(
    const short* __restrict__ lowq, const short* __restrict__ lowv,
    const short* __restrict__ Bq2, const short* __restrict__ Bv2,
    float* __restrict__ out) {
  const int lane = threadIdx.x & 63, wv = threadIdx.x >> 6;
  const int lrow = lane & 15, lk = lane >> 4;
  const int row0 = blockIdx.x * 64;
  const int m = blockIdx.y >> 1;
  const int half = blockIdx.y & 1;
  const short* low = m ? lowv : lowq;
  const short* B = m ? Bv2 : Bq2;
  float* op = out + (size_t)m * T_TOKENS * QOUT;

  s16x8 a[4][4];
#pragma unroll
  for (int rt = 0; rt < 4; ++rt)
#pragma unroll
    for (int kk = 0; kk < 4; ++kk)
      a[rt][kk] = *(const s16x8*)(low + (size_t)(row0 + rt * 16 + lrow) * 128 + kk * 32 + lk * 8);

  // prologue B load: (sub=0, kk=0)
  s16x8 bc[4], bn[4];
#pragma unroll
  for (int ct = 0; ct < 4; ++ct) {
    int c = half * 1024 + wv * 64 + ct * 16 + lrow;
    bc[ct] = *(const s16x8*)(B + ((size_t)lk * QOUT + c) * 8);
  }

  f32x4 acc[4][4] = {};
#pragma unroll
  for (int it = 0; it < 16; ++it) {
    const int sub = it >> 2, kk = it & 3;
    const int itn = (it + 1) & 15;           // wraps (dead) on last iter
    const int subn = itn >> 2, kkn = itn & 3;
    // issue next-iteration B loads before compute
#pragma unroll
    for (int ct = 0; ct < 4; ++ct) {
      int c = half * 1024 + subn * 256 + wv * 64 + ct * 16 + lrow;
      bn[ct] = *(const s16x8*)(B + ((size_t)(kkn * 4 + lk) * QOUT + c) * 8);
    }
#pragma unroll
    for (int rt = 0; rt < 4; ++rt)
#pragma unroll
      for (int ct = 0; ct < 4; ++ct)
        acc[rt][ct] = __builtin_amdgcn_mfma_f32_16x16x32_bf16(bc[ct], a[rt][kk], acc[rt][ct], 0, 0, 0);
    if (kk == 3) {
      int cb = half * 1024 + sub * 256 + wv * 64;
#pragma unroll
      for (int rt = 0; rt < 4; ++rt)
#pragma unroll
        for (int ct = 0; ct < 4; ++ct) {
          int t = row0 + rt * 16 + lrow;
          int col = cb + ct * 16 + lk * 4;
          __builtin_nontemporal_store(acc[rt][ct], (f32x4*)(op + (size_t)t * QOUT + col));
          acc[rt][ct] = (f32x4){0.f, 0.f, 0.f, 0.f};
        }
    }
#pragma unroll
    for (int ct = 0; ct < 4; ++ct) bc[ct] = bn[ct];
  }
}

extern "C" void kernel_launch(void* const* d_in, const int* in_sizes, int n_in,
                              void* d_out, int out_size, void* d_ws, size_t ws_size,
                              hipStream_t stream) {
  const float* h  = (const float*)d_in[0];
  const float* rw = (const float*)d_in[1];
  const float* qa = (const float*)d_in[2];
  const float* qb = (const float*)d_in[3];
  const float* va = (const float*)d_in[4];
  const float* vb = (const float*)d_in[5];
  float* out = (float*)d_out;
  char* ws = (char*)d_ws;

  short* Bq1 = (short*)(ws);                    // 512 KB each
  short* Bv1 = (short*)(ws + (512 << 10));
  short* Bq2 = (short*)(ws + (1024 << 10));
  short* Bv2 = (short*)(ws + (1536 << 10));
  short* lowq = (short*)(ws + (2 << 20));       // 4 MB each
  short* lowv = (short*)(ws + (6 << 20));

  k_pack<<<512, 256, 0, stream>>>(qa, qb, va, vb, Bq1, Bv1, Bq2, Bv2);
  k_s1<<<T_TOKENS / 32, 256, 0, stream>>>(h, rw, Bq1, Bv1, lowq, lowv);
  dim3 g2(T_TOKENS / 64, 4);
  k_up<<<g2, 256, 0, stream>>>(lowq, lowv, Bq2, Bv2, out);
}